// Round 9
// baseline (490.448 us; speedup 1.0000x reference)
//
#include <hip/hip_runtime.h>
#include <math.h>

#define BB 32
#define NN 1024
#define FF 10
#define DD 64
#define MM 4
#define RR 8
#define KK 20
#define BNROWS (BB*NN)   // 32768

// ---- workspace layout (float offsets) ----
#define OFF_HIT   0ull           // dead data region (kept as sc fallback scratch)
#define OFF_XLIN  2097152ull     // x_lin  [B,N,D]  2097152
#define OFF_EIT   4194304ull     // (dead)
#define OFF_PIT   4227072ull     // (unused; pi_t lives in d_out-adjacent ws? no: kept via stats)
#define OFF_MIXED 4227200ull     // mixed  [B,N,D]  2097152
#define OFF_SI    6324352ull     // s_i    [B,N]    32768
#define OFF_SJ    6357120ull     // s_j    [B,N]    32768
#define OFF_GNN   7700608ull     // gnn_pre [B,N,D] 2097152
#define OFF_OUTP  9797760ull     // out_pre [B,N,D] 2097152
#define OFF_STAT  11894912ull    // stats 256 | bstats 4096 | pnumb 16384 | pdenb 256 | cnt
#define OFF_SC    (OFF_STAT + 21008ull)  // score chunks

__device__ __forceinline__ float wave_sum(float v) {
    #pragma unroll
    for (int off = 32; off; off >>= 1) v += __shfl_xor(v, off);
    return v;
}
__device__ __forceinline__ float wave_max(float v) {
    #pragma unroll
    for (int off = 32; off; off >>= 1) v = fmaxf(v, __shfl_xor(v, off));
    return v;
}
__device__ __forceinline__ float lane_bcast(float v, int l) {
    return __int_as_float(__builtin_amdgcn_readlane(__float_as_int(v), l));
}

// ---- K1: per-row h/x + FUSED attention-pool partials (8-way banked atomics)
//         + last-block routing (replaces k_pool2 and k_route dispatches) ----
__global__ __launch_bounds__(256) void k_rows(
    const float* __restrict__ data, const float* __restrict__ W_cond,
    const float* __restrict__ b_cond, const float* __restrict__ W_ap,
    const float* __restrict__ b_ap, const float* __restrict__ W_av,
    const float* __restrict__ W_gnn, const float* __restrict__ W_r,
    const float* __restrict__ b_r, const float* __restrict__ gumbel,
    float* __restrict__ x_lin,
    float* pnumb, float* pdenb, unsigned* cnt,
    float* __restrict__ h_sys, float* __restrict__ pi_soft, float* __restrict__ pi_t)
{
    int tid = threadIdx.x;
    int w = tid >> 6, lane = tid & 63;
    int r = blockIdx.x * 4 + w;               // row in [0, B*N)
    int b = r >> 10;
    const float* dr = data + r * FF;
    float df[FF];
    #pragma unroll
    for (int f = 0; f < FF; f++) df[f] = dr[f];
    float h = b_cond[lane], x = 0.f;
    #pragma unroll
    for (int f = 0; f < FF; f++) {
        h = fmaf(df[f], W_cond[f * DD + lane], h);
        x = fmaf(df[f], W_gnn[f * DD + lane], x);
    }
    x_lin[(size_t)r * DD + lane] = x;
    // h @ W_ap via readlane broadcast (VALU, no LDS pipe)
    float acc = b_ap[lane];
    #pragma unroll
    for (int e2 = 0; e2 < DD; e2++)
        acc = fmaf(lane_bcast(h, e2), W_ap[e2 * DD + lane], acc);
    float lr2 = acc > 0.f ? acc : 0.2f * acc;
    float ep = wave_sum(lr2 * W_av[lane]);    // identical in all lanes
    // pool partial: softmax numerator/denominator, 8-way banked (fan-in 128/addr)
    float wgt = expf(ep);
    int bank = blockIdx.x & 7;
    atomicAdd(&pnumb[bank * 2048 + b * 64 + lane], wgt * h);
    if (lane == 0) atomicAdd(&pdenb[bank * 32 + b], wgt);

    // ---- last-block-done ticket -> routing tail (was k_route) ----
    __shared__ int is_last;
    __syncthreads();                          // drains this block's atomics (vmcnt)
    if (tid == 0) {
        __threadfence();
        unsigned old = atomicAdd(cnt, 1u);
        is_last = (old == (unsigned)(gridDim.x - 1)) ? 1 : 0;
    }
    __syncthreads();
    if (!is_last) return;
    __threadfence();                          // acquire all blocks' partials

    __shared__ float den_s[BB];
    if (tid < BB) {
        float d2 = 0.f;
        #pragma unroll
        for (int bk = 0; bk < 8; bk++) d2 += pdenb[bk * 32 + tid];
        den_s[tid] = d2;
    }
    __syncthreads();
    for (int i = tid; i < BB * DD; i += 256) {
        float s = 0.f;
        #pragma unroll
        for (int bk = 0; bk < 8; bk++) s += pnumb[bk * 2048 + i];
        h_sys[i] = s / den_s[i >> 6];
    }
    if (tid >= BB) return;
    int bb = tid;
    float inv = 1.0f / den_s[bb];
    float lg[MM];
    #pragma unroll
    for (int m = 0; m < MM; m++) lg[m] = b_r[m] + gumbel[bb * MM + m];
    for (int d = 0; d < DD; d++) {
        float s = 0.f;
        #pragma unroll
        for (int bk = 0; bk < 8; bk++) s += pnumb[bk * 2048 + bb * 64 + d];
        float hv = s * inv;
        #pragma unroll
        for (int m = 0; m < MM; m++) lg[m] = fmaf(hv, W_r[d * MM + m], lg[m]);
    }
    float mx = fmaxf(fmaxf(lg[0], lg[1]), fmaxf(lg[2], lg[3]));
    float s = 0.f, p[MM];
    #pragma unroll
    for (int m = 0; m < MM; m++) { p[m] = expf(lg[m] - mx); s += p[m]; }
    #pragma unroll
    for (int m = 0; m < MM; m++) { p[m] /= s; pi_soft[bb * MM + m] = p[m]; }
    int i1 = 0; float v1 = p[0];
    #pragma unroll
    for (int m = 1; m < MM; m++) if (p[m] > v1) { v1 = p[m]; i1 = m; }
    int i2 = -1; float v2 = -1.f;
    #pragma unroll
    for (int m = 0; m < MM; m++) if (m != i1 && p[m] > v2) { v2 = p[m]; i2 = m; }
    float norm = fmaxf(v1 + v2, 1e-12f);
    #pragma unroll
    for (int m = 0; m < MM; m++)
        pi_t[bb * MM + m] = (m == i1 ? v1 : (m == i2 ? v2 : 0.f)) / norm;
}

// ---------------- K3: mixed embeddings + s_i/s_j (wave per row) ----------------
__global__ __launch_bounds__(256) void k_mixed(
    const float* __restrict__ e_base, const float* __restrict__ lr_u,
    const float* __restrict__ lr_v, const float* __restrict__ pi_t,
    const float* __restrict__ x_lin,
    const float* __restrict__ att_i, const float* __restrict__ att_j,
    const float* __restrict__ att_em_i, const float* __restrict__ att_em_j,
    float* __restrict__ mixed, float* __restrict__ s_i, float* __restrict__ s_j)
{
    int w = threadIdx.x >> 6, lane = threadIdx.x & 63;
    int r = blockIdx.x * 4 + w;
    int b = r >> 10, n = r & 1023;
    float LR[MM];
    #pragma unroll
    for (int m = 0; m < MM; m++) {
        float a = 0.f;
        #pragma unroll
        for (int rr = 0; rr < RR; rr++)
            a = fmaf(lr_u[(m * NN + n) * RR + rr], lr_v[(m * RR + rr) * DD + lane], a);
        LR[m] = a;
    }
    float eb = e_base[n * DD + lane];
    float mx = 0.f;
    #pragma unroll
    for (int m = 0; m < MM; m++) mx = fmaf(pi_t[b * MM + m], eb + LR[m], mx);
    mixed[(size_t)r * DD + lane] = mx;
    float x = x_lin[(size_t)r * DD + lane];
    float r1 = wave_sum(x * att_i[lane] + mx * att_em_i[lane]);
    float r2 = wave_sum(x * att_j[lane] + mx * att_em_j[lane]);
    if (lane == 0) { s_i[r] = r1; s_j[r] = r2; }
}

// ---------------- K4a: score GEMM, 128x128, swizzled conflict-free LDS ----------------
__global__ __launch_bounds__(256) void k_score(
    const float* __restrict__ mixed_chunk, float* __restrict__ sc)
{
    __shared__ float As[32 * 132];
    __shared__ float Bs[32 * 132];
    int t = threadIdx.x;
    int bb = blockIdx.x >> 6;
    int rr = blockIdx.x & 63;
    int it = rr >> 3, jt = rr & 7;
    int i0 = it * 128, j0 = jt * 128;
    const float* mb = mixed_chunk + (size_t)bb * NN * DD;

    int tx = t & 15, ty = t >> 4;
    float acc[8][8];
    #pragma unroll
    for (int a = 0; a < 8; a++)
        #pragma unroll
        for (int bj = 0; bj < 8; bj++) acc[a][bj] = 0.f;

    int rowi[4], qi[4], swi[4];
    #pragma unroll
    for (int c = 0; c < 4; c++) {
        int id = t + c * 256;
        rowi[c] = (id & 15) | ((id >> 7) << 4);
        qi[c] = (id >> 4) & 7;
        swi[c] = ((rowi[c] & 4) << 4) | ((rowi[c] >> 3) << 2) | (rowi[c] & 3);
    }

    float4 pa[4], pb[4];
    #pragma unroll
    for (int c = 0; c < 4; c++) {
        pa[c] = *(const float4*)(mb + (size_t)(i0 + rowi[c]) * DD + qi[c] * 4);
        pb[c] = *(const float4*)(mb + (size_t)(j0 + rowi[c]) * DD + qi[c] * 4);
    }
    for (int hh = 0; hh < 2; hh++) {
        if (hh) __syncthreads();
        #pragma unroll
        for (int c = 0; c < 4; c++) {
            int pos = qi[c] * 4 * 132 + swi[c];
            As[pos] = pa[c].x; As[pos + 132] = pa[c].y; As[pos + 264] = pa[c].z; As[pos + 396] = pa[c].w;
            Bs[pos] = pb[c].x; Bs[pos + 132] = pb[c].y; Bs[pos + 264] = pb[c].z; Bs[pos + 396] = pb[c].w;
        }
        __syncthreads();
        if (hh == 0) {
            #pragma unroll
            for (int c = 0; c < 4; c++) {
                pa[c] = *(const float4*)(mb + (size_t)(i0 + rowi[c]) * DD + 32 + qi[c] * 4);
                pb[c] = *(const float4*)(mb + (size_t)(j0 + rowi[c]) * DD + 32 + qi[c] * 4);
            }
        }
        #pragma unroll 4
        for (int d = 0; d < 32; d++) {
            float4 a0 = *(const float4*)&As[d * 132 + ty * 4];
            float4 a1 = *(const float4*)&As[d * 132 + 64 + ty * 4];
            float4 b0 = *(const float4*)&Bs[d * 132 + tx * 4];
            float4 b1 = *(const float4*)&Bs[d * 132 + 64 + tx * 4];
            float av[8] = {a0.x, a0.y, a0.z, a0.w, a1.x, a1.y, a1.z, a1.w};
            float bv[8] = {b0.x, b0.y, b0.z, b0.w, b1.x, b1.y, b1.z, b1.w};
            #pragma unroll
            for (int a = 0; a < 8; a++)
                #pragma unroll
                for (int bj = 0; bj < 8; bj++)
                    acc[a][bj] = fmaf(av[a], bv[bj], acc[a][bj]);
        }
    }

    float* out = sc + ((size_t)bb * NN + i0 + ty * 8) * NN + j0 + tx * 8;
    #pragma unroll
    for (int a = 0; a < 8; a++) {
        float4 o0 = {acc[a][0], acc[a][1], acc[a][2], acc[a][3]};
        float4 o1 = {acc[a][4], acc[a][5], acc[a][6], acc[a][7]};
        *(float4*)(out + (size_t)a * NN) = o0;
        *(float4*)(out + (size_t)a * NN + 4) = o1;
    }
}

// ---------------- K4b: fused top-20 selection + GAT + banked bn1 stats ----------------
// (round-7 bitonic version — proven faster than ballot-radix: r8 post-mortem)
__global__ __launch_bounds__(256) void k_selgat(
    const float* __restrict__ sc, int b0,
    const float* __restrict__ x_lin, const float* __restrict__ s_i,
    const float* __restrict__ s_j, const float* __restrict__ b_gnn,
    float* __restrict__ gnn_pre, float* __restrict__ bstats)
{
    int w = threadIdx.x >> 6, lane = threadIdx.x & 63;
    int lr = blockIdx.x * 4 + w;
    int r = b0 * NN + lr;
    int b = r >> 10, n = r & 1023;
    const float* row = sc + (size_t)lr * NN;

    unsigned uk[16];
    #pragma unroll
    for (int c = 0; c < 4; c++) {
        float4 v = *(const float4*)(row + c * 256 + lane * 4);
        float vv[4] = {v.x, v.y, v.z, v.w};
        #pragma unroll
        for (int q = 0; q < 4; q++) {
            unsigned u = __float_as_uint(vv[q]);
            uk[c * 4 + q] = u ^ (((unsigned)((int)u >> 31)) | 0x80000000u);
        }
    }
    unsigned mx = uk[0];
    #pragma unroll
    for (int i = 1; i < 16; i++) mx = uk[i] > mx ? uk[i] : mx;
    unsigned sv = mx;
    #pragma unroll
    for (int blk = 2; blk <= 64; blk <<= 1) {
        #pragma unroll
        for (int dist = blk >> 1; dist >= 1; dist >>= 1) {
            unsigned pv = (unsigned)__shfl_xor((int)sv, dist);
            bool up = (lane & blk) == 0;
            bool upper = (lane & dist) == 0;
            bool g = sv > pv;
            sv = (((g == upper) == up)) ? sv : pv;
        }
    }
    unsigned tau = (unsigned)__shfl((int)sv, 19);

    __shared__ unsigned skey[4][64];
    __shared__ int sjj[4][64];
    int base = 0;
    #pragma unroll
    for (int s = 0; s < 16; s++) {
        bool q = uk[s] >= tau;
        unsigned long long m = __ballot(q);
        if (q) {
            int pos = base + __popcll(m & ((1ull << lane) - 1ull));
            if (pos < 64) {
                skey[w][pos] = uk[s];
                sjj[w][pos] = ((s >> 2) << 8) + lane * 4 + (s & 3);
            }
        }
        base += __popcll(m);
    }
    int C = base;

    float vk = -INFINITY; int ik = 0;
    if (C <= 64) {
        unsigned ck = 0u; int cj = 0x7FFFFFFF;
        if (lane < C) { ck = skey[w][lane]; cj = sjj[w][lane]; }
        if (C <= 32) {
            #pragma unroll
            for (int blk = 2; blk <= 32; blk <<= 1)
                #pragma unroll
                for (int dist = blk >> 1; dist >= 1; dist >>= 1) {
                    unsigned pk = (unsigned)__shfl_xor((int)ck, dist);
                    int pj = __shfl_xor(cj, dist);
                    bool up = (lane & blk) == 0;
                    bool upper = (lane & dist) == 0;
                    bool g = (ck > pk) || (ck == pk && cj < pj);
                    bool keep = ((g == upper) == up);
                    ck = keep ? ck : pk; cj = keep ? cj : pj;
                }
        } else {
            #pragma unroll
            for (int blk = 2; blk <= 64; blk <<= 1)
                #pragma unroll
                for (int dist = blk >> 1; dist >= 1; dist >>= 1) {
                    unsigned pk = (unsigned)__shfl_xor((int)ck, dist);
                    int pj = __shfl_xor(cj, dist);
                    bool up = (lane & blk) == 0;
                    bool upper = (lane & dist) == 0;
                    bool g = (ck > pk) || (ck == pk && cj < pj);
                    bool keep = ((g == upper) == up);
                    ck = keep ? ck : pk; cj = keep ? cj : pj;
                }
        }
        if (lane < KK) {
            unsigned u = (ck & 0x80000000u) ? (ck ^ 0x80000000u) : ~ck;
            vk = __uint_as_float(u);
            ik = cj;
        }
    } else {
        for (int k = 0; k < KK; k++) {
            unsigned bm = uk[0]; int bsl = 0;
            #pragma unroll
            for (int i = 1; i < 16; i++) if (uk[i] > bm) { bm = uk[i]; bsl = i; }
            unsigned wm = bm;
            #pragma unroll
            for (int off = 32; off; off >>= 1) {
                unsigned tt = (unsigned)__shfl_xor((int)wm, off);
                wm = tt > wm ? tt : wm;
            }
            unsigned long long ball = __ballot(bm == wm);
            int winner = (int)__builtin_ctzll(ball);
            int slotw = __shfl(bsl, winner);
            int jw = ((slotw >> 2) << 8) + winner * 4 + (slotw & 3);
            unsigned u2 = (wm & 0x80000000u) ? (wm ^ 0x80000000u) : ~wm;
            if (lane == k) { vk = __uint_as_float(u2); ik = jw; }
            if (lane == winner) uk[bsl] = 0u;
        }
    }

    float m1 = wave_max(vk);
    float ek = (lane < KK) ? expf(vk - m1) : 0.f;
    float s1v = wave_sum(ek);
    float wk = ek / s1v;
    float si = s_i[r], sjn = s_j[r];
    float a = -INFINITY;
    if (lane < KK) {
        float sjk = s_j[(b << 10) + ik];
        float t2 = si + sjk;
        a = (ik == n) ? -INFINITY : (t2 > 0.f ? t2 : 0.2f * t2);
    }
    float ts = si + sjn;
    float aself = ts > 0.f ? ts : 0.2f * ts;
    float am = wave_max(fmaxf(a, aself));
    float ea = (lane < KK && a != -INFINITY) ? expf(a - am) : 0.f;
    float es = expf(aself - am);
    float ssm = wave_sum(ea) + es;
    float wnb = (ea / ssm) * wk;
    float wself = es / ssm;
    float acc = b_gnn[lane] + wself * x_lin[(size_t)r * DD + lane];
    #pragma unroll
    for (int k = 0; k < KK; k++) {
        int jk = __shfl(ik, k);
        float wv = __shfl(wnb, k);
        acc = fmaf(wv, x_lin[((size_t)(b << 10) + jk) * DD + lane], acc);
    }
    gnn_pre[(size_t)r * DD + lane] = acc;

    __shared__ float ps[4][64], pq[4][64];
    ps[w][lane] = acc;
    pq[w][lane] = acc * acc;
    __syncthreads();
    if (w == 0) {
        float s = ps[0][lane] + ps[1][lane] + ps[2][lane] + ps[3][lane];
        float q2 = pq[0][lane] + pq[1][lane] + pq[2][lane] + pq[3][lane];
        float* bk = bstats + (size_t)(blockIdx.x & 31) * 128;
        atomicAdd(&bk[lane], s);
        atomicAdd(&bk[DD + lane], q2);
    }
}

// ---------------- K7: bn1 + relu + embed multiply (+ bno stats partials) ----------------
__global__ __launch_bounds__(256) void k_bn1(
    const float* __restrict__ gnn_pre, float* __restrict__ stats,
    const float* __restrict__ bstats,
    const float* __restrict__ gamma, const float* __restrict__ beta,
    const float* __restrict__ net, float* __restrict__ out_pre)
{
    int tid = threadIdx.x;
    int d0 = (tid & 15) * 4;
    float mean4[4], rs4[4], bt4[4];
    #pragma unroll
    for (int k = 0; k < 4; k++) {
        float s = 0.f, q = 0.f;
        #pragma unroll 8
        for (int bk = 0; bk < 32; bk++) {
            s += bstats[bk * 128 + d0 + k];
            q += bstats[bk * 128 + 64 + d0 + k];
        }
        float mu = s * (1.0f / BNROWS);
        float var = q * (1.0f / BNROWS) - mu * mu;
        mean4[k] = mu;
        rs4[k] = rsqrtf(var + 1e-5f) * gamma[d0 + k];
        bt4[k] = beta[d0 + k];
    }
    float s4[4] = {0, 0, 0, 0}, q4[4] = {0, 0, 0, 0};
    size_t base4 = (size_t)blockIdx.x * 2048;
    #pragma unroll
    for (int i = 0; i < 8; i++) {
        size_t f4 = base4 + (size_t)i * 256 + tid;
        float4 v = ((const float4*)gnn_pre)[f4];
        int n = ((int)(f4 >> 4)) & 1023;
        float4 nv = ((const float4*)net)[(size_t)n * 16 + (tid & 15)];
        float vv[4] = {v.x, v.y, v.z, v.w};
        float nn2[4] = {nv.x, nv.y, nv.z, nv.w};
        float ov[4];
        #pragma unroll
        for (int k = 0; k < 4; k++) {
            float y = (vv[k] - mean4[k]) * rs4[k] + bt4[k];
            y = y > 0.f ? y : 0.f;
            float o = y * nn2[k];
            ov[k] = o;
            s4[k] += o;
            q4[k] = fmaf(o, o, q4[k]);
        }
        float4 o4 = {ov[0], ov[1], ov[2], ov[3]};
        ((float4*)out_pre)[f4] = o4;
    }
    __shared__ float4 ls[256], lq[256];
    ls[tid] = make_float4(s4[0], s4[1], s4[2], s4[3]);
    lq[tid] = make_float4(q4[0], q4[1], q4[2], q4[3]);
    __syncthreads();
    if (tid < 16) {
        float4 S = ls[tid], Q = lq[tid];
        #pragma unroll
        for (int rr = 1; rr < 16; rr++) {
            float4 a = ls[tid + 16 * rr], b = lq[tid + 16 * rr];
            S.x += a.x; S.y += a.y; S.z += a.z; S.w += a.w;
            Q.x += b.x; Q.y += b.y; Q.z += b.z; Q.w += b.w;
        }
        atomicAdd(&stats[128 + tid * 4 + 0], S.x);
        atomicAdd(&stats[128 + tid * 4 + 1], S.y);
        atomicAdd(&stats[128 + tid * 4 + 2], S.z);
        atomicAdd(&stats[128 + tid * 4 + 3], S.w);
        atomicAdd(&stats[192 + tid * 4 + 0], Q.x);
        atomicAdd(&stats[192 + tid * 4 + 1], Q.y);
        atomicAdd(&stats[192 + tid * 4 + 2], Q.z);
        atomicAdd(&stats[192 + tid * 4 + 3], Q.w);
    }
}

// ---------------- K8: bn_out + relu + head ----------------
__global__ __launch_bounds__(256) void k_head(
    const float* __restrict__ out_pre, const float* __restrict__ stats,
    const float* __restrict__ gamma, const float* __restrict__ beta,
    const float* __restrict__ W_out, const float* __restrict__ b_out,
    float* __restrict__ out)
{
    int w = threadIdx.x >> 6, lane = threadIdx.x & 63;
    int r = blockIdx.x * 4 + w;
    float mean = stats[lane] * (1.0f / BNROWS);
    float var = stats[DD + lane] * (1.0f / BNROWS) - mean * mean;
    float rs = rsqrtf(var + 1e-5f);
    float y = (out_pre[(size_t)r * DD + lane] - mean) * rs * gamma[lane] + beta[lane];
    y = y > 0.f ? y : 0.f;
    float p = wave_sum(y * W_out[lane]);
    if (lane == 0) out[r] = p + b_out[0];
}

extern "C" void kernel_launch(void* const* d_in, const int* in_sizes, int n_in,
                              void* d_out, int out_size, void* d_ws, size_t ws_size,
                              hipStream_t stream)
{
    const float* data     = (const float*)d_in[0];
    const float* gumbel   = (const float*)d_in[1];
    const float* W_cond   = (const float*)d_in[2];
    const float* b_cond   = (const float*)d_in[3];
    const float* W_ap     = (const float*)d_in[4];
    const float* b_ap     = (const float*)d_in[5];
    const float* W_av     = (const float*)d_in[6];
    const float* W_r      = (const float*)d_in[7];
    const float* b_r      = (const float*)d_in[8];
    const float* e_base   = (const float*)d_in[9];
    const float* lr_u     = (const float*)d_in[10];
    const float* lr_v     = (const float*)d_in[11];
    const float* W_gnn    = (const float*)d_in[12];
    const float* att_i    = (const float*)d_in[13];
    const float* att_j    = (const float*)d_in[14];
    const float* att_em_i = (const float*)d_in[15];
    const float* att_em_j = (const float*)d_in[16];
    const float* b_gnn    = (const float*)d_in[17];
    const float* bn1_g    = (const float*)d_in[18];
    const float* bn1_b    = (const float*)d_in[19];
    const float* net      = (const float*)d_in[20];
    const float* bno_g    = (const float*)d_in[21];
    const float* bno_b    = (const float*)d_in[22];
    const float* W_out    = (const float*)d_in[23];
    const float* b_out    = (const float*)d_in[24];

    float* ws = (float*)d_ws;
    float* x_lin  = ws + OFF_XLIN;
    float* pi_tb  = ws + OFF_PIT;            // pi_t  [B,M]
    float* mixed  = ws + OFF_MIXED;
    float* s_i    = ws + OFF_SI;
    float* s_j    = ws + OFF_SJ;
    float* gnn_pre = ws + OFF_GNN;
    float* out_pre = ws + OFF_OUTP;
    float* stats   = ws + OFF_STAT;          // 256: [128..255] bno stats
    float* bstats  = stats + 256;            // 32 banks x 128 (bn1 sum/sumsq)
    float* pnumb   = stats + 4352;           // 8 banks x 32 x 64
    float* pdenb   = stats + 20736;          // 8 banks x 32
    unsigned* cnt  = (unsigned*)(stats + 20992);

    float* out0    = (float*)d_out;
    float* h_sys   = out0 + BB * NN;              // 32768
    float* pi_soft = out0 + BB * NN + BB * DD;    // 34816

    // zero accumulators (stats 256 + bstats 4096 + pnumb 16384 + pdenb 256 + cnt)
    hipMemsetAsync(stats, 0, 21000 * sizeof(float), stream);

    k_rows<<<BNROWS / 4, 256, 0, stream>>>(data, W_cond, b_cond, W_ap, b_ap, W_av, W_gnn,
                                           W_r, b_r, gumbel, x_lin,
                                           pnumb, pdenb, cnt, h_sys, pi_soft, pi_tb);
    k_mixed<<<BNROWS / 4, 256, 0, stream>>>(e_base, lr_u, lr_v, pi_tb, x_lin,
                                            att_i, att_j, att_em_i, att_em_j, mixed, s_i, s_j);

    // ---- chunked score GEMM + fused selection/GAT (+banked bn1 stats) ----
    size_t ws_floats = ws_size / 4;
    size_t avail = ws_floats > OFF_SC ? ws_floats - OFF_SC : 0;
    int cb = (int)(avail / (size_t)(NN * NN));
    if (cb > BB) cb = BB;
    float* sc = ws + OFF_SC;
    if (cb < 1) { cb = 2; sc = ws + OFF_HIT; }   // OFF_HIT region is dead scratch
    for (int b0 = 0; b0 < BB; b0 += cb) {
        int c = (BB - b0) < cb ? (BB - b0) : cb;
        k_score<<<c * 64, 256, 0, stream>>>(mixed + (size_t)b0 * NN * DD, sc);
        k_selgat<<<c * 256, 256, 0, stream>>>(sc, b0, x_lin, s_i, s_j, b_gnn, gnn_pre, bstats);
    }

    k_bn1<<<256, 256, 0, stream>>>(gnn_pre, stats, bstats, bn1_g, bn1_b, net, out_pre);
    k_head<<<BNROWS / 4, 256, 0, stream>>>(out_pre, stats + 128, bno_g, bno_b, W_out, b_out, out0);
}

// Round 10
// 358.505 us; speedup vs baseline: 1.3680x; 1.3680x over previous
//
#include <hip/hip_runtime.h>
#include <math.h>

#define BB 32
#define NN 1024
#define FF 10
#define DD 64
#define MM 4
#define RR 8
#define KK 20
#define BNROWS (BB*NN)   // 32768

// ---- workspace layout (float offsets) ----
#define OFF_HIT   0ull           // h_it   [B,N,D]  2097152
#define OFF_XLIN  2097152ull     // x_lin  [B,N,D]  2097152
#define OFF_EIT   4194304ull     // e_it   [B,N]    32768
#define OFF_PIT   4227072ull     // pi_t   [B,M]    128
#define OFF_MIXED 4227200ull     // mixed  [B,N,D]  2097152
#define OFF_SI    6324352ull     // s_i    [B,N]    32768
#define OFF_SJ    6357120ull     // s_j    [B,N]    32768
#define OFF_GNN   7700608ull     // gnn_pre [B,N,D] 2097152
#define OFF_OUTP  9797760ull     // out_pre [B,N,D] 2097152
#define OFF_STAT  11894912ull    // stats 256 + banked bn1 4096 + pool num 2048 + den 32
#define OFF_SC    (OFF_STAT + 6464ull)  // score chunks

__device__ __forceinline__ float wave_sum(float v) {
    #pragma unroll
    for (int off = 32; off; off >>= 1) v += __shfl_xor(v, off);
    return v;
}
__device__ __forceinline__ float wave_max(float v) {
    #pragma unroll
    for (int off = 32; off; off >>= 1) v = fmaxf(v, __shfl_xor(v, off));
    return v;
}
__device__ __forceinline__ float lane_bcast(float v, int l) {
    return __int_as_float(__builtin_amdgcn_readlane(__float_as_int(v), l));
}

// ---------------- K1a: per-row h_it, x_lin, e_it (+ zero accum buffers) ----------------
__global__ __launch_bounds__(256) void k_rows(
    const float* __restrict__ data, const float* __restrict__ W_cond,
    const float* __restrict__ b_cond, const float* __restrict__ W_ap,
    const float* __restrict__ b_ap, const float* __restrict__ W_av,
    const float* __restrict__ W_gnn,
    float* __restrict__ h_it, float* __restrict__ x_lin, float* __restrict__ e_it,
    float* __restrict__ stats)
{
    if (blockIdx.x < 26) {
        int idx = blockIdx.x * 256 + threadIdx.x;
        if (idx < 6432) stats[idx] = 0.f;    // stats(256)+banked(4096)+num(2048)+den(32)
    }
    int w = threadIdx.x >> 6, lane = threadIdx.x & 63;
    int r = blockIdx.x * 4 + w;               // row in [0, B*N)
    const float* dr = data + r * FF;
    float df[FF];
    #pragma unroll
    for (int f = 0; f < FF; f++) df[f] = dr[f];
    float h = b_cond[lane], x = 0.f;
    #pragma unroll
    for (int f = 0; f < FF; f++) {
        h = fmaf(df[f], W_cond[f * DD + lane], h);
        x = fmaf(df[f], W_gnn[f * DD + lane], x);
    }
    h_it[r * DD + lane] = h;
    x_lin[r * DD + lane] = x;
    // h @ W_ap via readlane broadcast (VALU) instead of __shfl (LDS pipe)
    float acc = b_ap[lane];
    #pragma unroll
    for (int e2 = 0; e2 < DD; e2++)
        acc = fmaf(lane_bcast(h, e2), W_ap[e2 * DD + lane], acc);
    float lr = acc > 0.f ? acc : 0.2f * acc;
    float ep = wave_sum(lr * W_av[lane]);
    if (lane == 0) e_it[r] = ep;
}

// ---------------- K1b: parallel pool partials (no max shift; |e| small) ----------------
__global__ __launch_bounds__(256) void k_pool2(
    const float* __restrict__ e_it, const float* __restrict__ h_it,
    float* __restrict__ num, float* __restrict__ den)
{
    int w = threadIdx.x >> 6, lane = threadIdx.x & 63;
    int b = blockIdx.x >> 3, ch = blockIdx.x & 7;
    int base = b * NN + ch * 128 + w * 32;
    float acc = 0.f, dn = 0.f;
    #pragma unroll 4
    for (int i = 0; i < 32; i++) {
        float e = e_it[base + i];
        float wgt = expf(e);
        acc = fmaf(wgt, h_it[(size_t)(base + i) * DD + lane], acc);
        dn += wgt;
    }
    __shared__ float pa[4][DD];
    __shared__ float pd[4];
    pa[w][lane] = acc;
    if (lane == 0) pd[w] = dn;
    __syncthreads();
    if (w == 0) {
        float s = pa[0][lane] + pa[1][lane] + pa[2][lane] + pa[3][lane];
        atomicAdd(&num[b * DD + lane], s);
        if (lane == 0) atomicAdd(&den[b], pd[0] + pd[1] + pd[2] + pd[3]);
    }
}

// ---------------- K2: routing + h_sys normalize ----------------
__global__ void k_route(const float* __restrict__ num, const float* __restrict__ den,
                        const float* __restrict__ W_r, const float* __restrict__ b_r,
                        const float* __restrict__ gumbel,
                        float* __restrict__ h_sys, float* __restrict__ pi_soft,
                        float* __restrict__ pi_t)
{
    int tid = threadIdx.x;
    for (int i = tid; i < BB * DD; i += 256)
        h_sys[i] = num[i] / den[i >> 6];
    if (tid >= BB) return;
    int b = tid;
    float inv = 1.0f / den[b];
    float lg[MM];
    #pragma unroll
    for (int m = 0; m < MM; m++) lg[m] = b_r[m] + gumbel[b * MM + m];
    for (int d = 0; d < DD; d++) {
        float hv = num[b * DD + d] * inv;
        #pragma unroll
        for (int m = 0; m < MM; m++) lg[m] = fmaf(hv, W_r[d * MM + m], lg[m]);
    }
    float mx = fmaxf(fmaxf(lg[0], lg[1]), fmaxf(lg[2], lg[3]));
    float s = 0.f, p[MM];
    #pragma unroll
    for (int m = 0; m < MM; m++) { p[m] = expf(lg[m] - mx); s += p[m]; }
    #pragma unroll
    for (int m = 0; m < MM; m++) { p[m] /= s; pi_soft[b * MM + m] = p[m]; }
    int i1 = 0; float v1 = p[0];
    #pragma unroll
    for (int m = 1; m < MM; m++) if (p[m] > v1) { v1 = p[m]; i1 = m; }
    int i2 = -1; float v2 = -1.f;
    #pragma unroll
    for (int m = 0; m < MM; m++) if (m != i1 && p[m] > v2) { v2 = p[m]; i2 = m; }
    float norm = fmaxf(v1 + v2, 1e-12f);
    #pragma unroll
    for (int m = 0; m < MM; m++)
        pi_t[b * MM + m] = (m == i1 ? v1 : (m == i2 ? v2 : 0.f)) / norm;
}

// ---------------- K3: mixed embeddings + s_i/s_j (wave per row) ----------------
__global__ __launch_bounds__(256) void k_mixed(
    const float* __restrict__ e_base, const float* __restrict__ lr_u,
    const float* __restrict__ lr_v, const float* __restrict__ pi_t,
    const float* __restrict__ x_lin,
    const float* __restrict__ att_i, const float* __restrict__ att_j,
    const float* __restrict__ att_em_i, const float* __restrict__ att_em_j,
    float* __restrict__ mixed, float* __restrict__ s_i, float* __restrict__ s_j)
{
    int w = threadIdx.x >> 6, lane = threadIdx.x & 63;
    int r = blockIdx.x * 4 + w;
    int b = r >> 10, n = r & 1023;
    float LR[MM];
    #pragma unroll
    for (int m = 0; m < MM; m++) {
        float a = 0.f;
        #pragma unroll
        for (int rr = 0; rr < RR; rr++)
            a = fmaf(lr_u[(m * NN + n) * RR + rr], lr_v[(m * RR + rr) * DD + lane], a);
        LR[m] = a;
    }
    float eb = e_base[n * DD + lane];
    float mx = 0.f;
    #pragma unroll
    for (int m = 0; m < MM; m++) mx = fmaf(pi_t[b * MM + m], eb + LR[m], mx);
    mixed[(size_t)r * DD + lane] = mx;
    float x = x_lin[(size_t)r * DD + lane];
    float r1 = wave_sum(x * att_i[lane] + mx * att_em_i[lane]);
    float r2 = wave_sum(x * att_j[lane] + mx * att_em_j[lane]);
    if (lane == 0) { s_i[r] = r1; s_j[r] = r2; }
}

// ---------------- K4a v2: score GEMM, 32x256 tile, A wave-uniform from global ----------
// Wave w owns rows i0+w*8..+7 -> A addresses are wave-uniform (one L1 transaction, no
// LDS). Only B staged: BT[d][col] (pad 264), K in 2 halves of 32d, reg-prefetched.
// Per d per lane: ONE ds_read_b128 (cols lane*4..+3, conflict-free) + 128 FMA/wave.
// LDS/wave/d drops 4 b128 -> 1 vs v1 => VALU-bound (v1 was LDS-pipe-bound at 53% VALU).
__global__ __launch_bounds__(256) void k_score(
    const float* __restrict__ mixed_chunk, float* __restrict__ sc)
{
    __shared__ float BT[32 * 264];     // 33792 B
    int t = threadIdx.x;
    int w = t >> 6, lane = t & 63;
    int bb = blockIdx.x >> 7;
    int rr = blockIdx.x & 127;
    int it = rr >> 2, jt = rr & 3;
    int i0 = it * 32, j0 = jt * 256;
    const float* mb = mixed_chunk + (size_t)bb * NN * DD;
    const float* arow = mb + (size_t)(i0 + w * 8) * DD;   // wave-uniform A base

    float4 acc4[8];
    #pragma unroll
    for (int a = 0; a < 8; a++) acc4[a] = make_float4(0.f, 0.f, 0.f, 0.f);

    // staging: thread t owns col j0+t, loads its d-half [dh, dh+32) = 8 float4 (128B)
    float4 pf[8];
    {
        const float* src = mb + (size_t)(j0 + t) * DD;    // half 0: dh = 0
        #pragma unroll
        for (int i = 0; i < 8; i++) pf[i] = *(const float4*)(src + i * 4);
    }
    for (int hh = 0; hh < 2; hh++) {
        if (hh) __syncthreads();
        // write BT[d][t]: 8-lane phases hit 8 consecutive banks -> conflict-free
        #pragma unroll
        for (int i = 0; i < 8; i++) {
            float4 v = pf[i];
            int d0 = i * 4;
            BT[(d0 + 0) * 264 + t] = v.x;
            BT[(d0 + 1) * 264 + t] = v.y;
            BT[(d0 + 2) * 264 + t] = v.z;
            BT[(d0 + 3) * 264 + t] = v.w;
        }
        __syncthreads();
        if (hh == 0) {                 // prefetch half 1 during compute of half 0
            const float* src = mb + (size_t)(j0 + t) * DD + 32;
            #pragma unroll
            for (int i = 0; i < 8; i++) pf[i] = *(const float4*)(src + i * 4);
        }
        int dh = hh * 32;
        #pragma unroll 2
        for (int d4 = 0; d4 < 8; d4++) {
            float4 av[8];
            #pragma unroll
            for (int a = 0; a < 8; a++)
                av[a] = *(const float4*)(arow + (size_t)a * DD + dh + d4 * 4);
            #pragma unroll
            for (int dd = 0; dd < 4; dd++) {
                float4 bv = *(const float4*)&BT[(d4 * 4 + dd) * 264 + lane * 4];
                #pragma unroll
                for (int a = 0; a < 8; a++) {
                    float as = dd == 0 ? av[a].x : dd == 1 ? av[a].y : dd == 2 ? av[a].z : av[a].w;
                    acc4[a].x = fmaf(as, bv.x, acc4[a].x);
                    acc4[a].y = fmaf(as, bv.y, acc4[a].y);
                    acc4[a].z = fmaf(as, bv.z, acc4[a].z);
                    acc4[a].w = fmaf(as, bv.w, acc4[a].w);
                }
            }
        }
    }

    float* out = sc + ((size_t)bb * NN + i0 + w * 8) * NN + j0 + lane * 4;
    #pragma unroll
    for (int a = 0; a < 8; a++)
        *(float4*)(out + (size_t)a * NN) = acc4[a];
}

// ---------------- K4b: fused top-20 selection + GAT + banked bn1 stats ----------------
// wave per row. slot s of lane l -> j = (s>>2)*256 + l*4 + (s&3)
__global__ __launch_bounds__(256) void k_selgat(
    const float* __restrict__ sc, int b0,
    const float* __restrict__ x_lin, const float* __restrict__ s_i,
    const float* __restrict__ s_j, const float* __restrict__ b_gnn,
    float* __restrict__ gnn_pre, float* __restrict__ bstats)
{
    int w = threadIdx.x >> 6, lane = threadIdx.x & 63;
    int lr = blockIdx.x * 4 + w;                 // local row within chunk
    int r = b0 * NN + lr;                        // global row
    int b = r >> 10, n = r & 1023;
    const float* row = sc + (size_t)lr * NN;

    unsigned uk[16];
    #pragma unroll
    for (int c = 0; c < 4; c++) {
        float4 v = *(const float4*)(row + c * 256 + lane * 4);
        float vv[4] = {v.x, v.y, v.z, v.w};
        #pragma unroll
        for (int q = 0; q < 4; q++) {
            unsigned u = __float_as_uint(vv[q]);
            uk[c * 4 + q] = u ^ (((unsigned)((int)u >> 31)) | 0x80000000u);
        }
    }
    unsigned mx = uk[0];
    #pragma unroll
    for (int i = 1; i < 16; i++) mx = uk[i] > mx ? uk[i] : mx;
    unsigned sv = mx;
    #pragma unroll
    for (int blk = 2; blk <= 64; blk <<= 1) {
        #pragma unroll
        for (int dist = blk >> 1; dist >= 1; dist >>= 1) {
            unsigned pv = (unsigned)__shfl_xor((int)sv, dist);
            bool up = (lane & blk) == 0;
            bool upper = (lane & dist) == 0;
            bool g = sv > pv;
            sv = (((g == upper) == up)) ? sv : pv;
        }
    }
    unsigned tau = (unsigned)__shfl((int)sv, 19);

    __shared__ unsigned skey[4][64];
    __shared__ int sjj[4][64];
    int base = 0;
    #pragma unroll
    for (int s = 0; s < 16; s++) {
        bool q = uk[s] >= tau;
        unsigned long long m = __ballot(q);
        if (q) {
            int pos = base + __popcll(m & ((1ull << lane) - 1ull));
            if (pos < 64) {
                skey[w][pos] = uk[s];
                sjj[w][pos] = ((s >> 2) << 8) + lane * 4 + (s & 3);
            }
        }
        base += __popcll(m);
    }
    int C = base;   // >= 20 guaranteed

    float vk = -INFINITY; int ik = 0;
    if (C <= 64) {
        unsigned ck = 0u; int cj = 0x7FFFFFFF;
        if (lane < C) { ck = skey[w][lane]; cj = sjj[w][lane]; }
        if (C <= 32) {
            #pragma unroll
            for (int blk = 2; blk <= 32; blk <<= 1)
                #pragma unroll
                for (int dist = blk >> 1; dist >= 1; dist >>= 1) {
                    unsigned pk = (unsigned)__shfl_xor((int)ck, dist);
                    int pj = __shfl_xor(cj, dist);
                    bool up = (lane & blk) == 0;
                    bool upper = (lane & dist) == 0;
                    bool g = (ck > pk) || (ck == pk && cj < pj);
                    bool keep = ((g == upper) == up);
                    ck = keep ? ck : pk; cj = keep ? cj : pj;
                }
        } else {
            #pragma unroll
            for (int blk = 2; blk <= 64; blk <<= 1)
                #pragma unroll
                for (int dist = blk >> 1; dist >= 1; dist >>= 1) {
                    unsigned pk = (unsigned)__shfl_xor((int)ck, dist);
                    int pj = __shfl_xor(cj, dist);
                    bool up = (lane & blk) == 0;
                    bool upper = (lane & dist) == 0;
                    bool g = (ck > pk) || (ck == pk && cj < pj);
                    bool keep = ((g == upper) == up);
                    ck = keep ? ck : pk; cj = keep ? cj : pj;
                }
        }
        if (lane < KK) {
            unsigned u = (ck & 0x80000000u) ? (ck ^ 0x80000000u) : ~ck;
            vk = __uint_as_float(u);
            ik = cj;
        }
    } else {
        for (int k = 0; k < KK; k++) {
            unsigned bm = uk[0]; int bsl = 0;
            #pragma unroll
            for (int i = 1; i < 16; i++) if (uk[i] > bm) { bm = uk[i]; bsl = i; }
            unsigned wm = bm;
            #pragma unroll
            for (int off = 32; off; off >>= 1) {
                unsigned tt = (unsigned)__shfl_xor((int)wm, off);
                wm = tt > wm ? tt : wm;
            }
            unsigned long long ball = __ballot(bm == wm);
            int winner = (int)__builtin_ctzll(ball);
            int slotw = __shfl(bsl, winner);
            int jw = ((slotw >> 2) << 8) + winner * 4 + (slotw & 3);
            unsigned u2 = (wm & 0x80000000u) ? (wm ^ 0x80000000u) : ~wm;
            if (lane == k) { vk = __uint_as_float(u2); ik = jw; }
            if (lane == winner) uk[bsl] = 0u;
        }
    }

    float m1 = wave_max(vk);
    float ek = (lane < KK) ? expf(vk - m1) : 0.f;
    float s1v = wave_sum(ek);
    float wk = ek / s1v;
    float si = s_i[r], sjn = s_j[r];
    float a = -INFINITY;
    if (lane < KK) {
        float sjk = s_j[(b << 10) + ik];
        float t2 = si + sjk;
        a = (ik == n) ? -INFINITY : (t2 > 0.f ? t2 : 0.2f * t2);
    }
    float ts = si + sjn;
    float aself = ts > 0.f ? ts : 0.2f * ts;
    float am = wave_max(fmaxf(a, aself));
    float ea = (lane < KK && a != -INFINITY) ? expf(a - am) : 0.f;
    float es = expf(aself - am);
    float ssm = wave_sum(ea) + es;
    float wnb = (ea / ssm) * wk;
    float wself = es / ssm;
    float acc = b_gnn[lane] + wself * x_lin[(size_t)r * DD + lane];
    #pragma unroll
    for (int k = 0; k < KK; k++) {
        int jk = __shfl(ik, k);
        float wv = __shfl(wnb, k);
        acc = fmaf(wv, x_lin[((size_t)(b << 10) + jk) * DD + lane], acc);
    }
    gnn_pre[(size_t)r * DD + lane] = acc;

    // bn1 stats partials, 32-way banked (r6 lesson: single-line fan-in serializes)
    __shared__ float ps[4][64], pq[4][64];
    ps[w][lane] = acc;
    pq[w][lane] = acc * acc;
    __syncthreads();
    if (w == 0) {
        float s = ps[0][lane] + ps[1][lane] + ps[2][lane] + ps[3][lane];
        float q2 = pq[0][lane] + pq[1][lane] + pq[2][lane] + pq[3][lane];
        float* bk = bstats + (size_t)(blockIdx.x & 31) * 128;
        atomicAdd(&bk[lane], s);
        atomicAdd(&bk[DD + lane], q2);
    }
}

// ---------------- K7: bn1 + relu + embed multiply (+ bno stats partials) ----------------
__global__ __launch_bounds__(256) void k_bn1(
    const float* __restrict__ gnn_pre, float* __restrict__ stats,
    const float* __restrict__ bstats,
    const float* __restrict__ gamma, const float* __restrict__ beta,
    const float* __restrict__ net, float* __restrict__ out_pre)
{
    int tid = threadIdx.x;
    int d0 = (tid & 15) * 4;
    float mean4[4], rs4[4], bt4[4];
    #pragma unroll
    for (int k = 0; k < 4; k++) {
        float s = 0.f, q = 0.f;
        #pragma unroll 8
        for (int bk = 0; bk < 32; bk++) {
            s += bstats[bk * 128 + d0 + k];
            q += bstats[bk * 128 + 64 + d0 + k];
        }
        float mu = s * (1.0f / BNROWS);
        float var = q * (1.0f / BNROWS) - mu * mu;
        mean4[k] = mu;
        rs4[k] = rsqrtf(var + 1e-5f) * gamma[d0 + k];
        bt4[k] = beta[d0 + k];
    }
    float s4[4] = {0, 0, 0, 0}, q4[4] = {0, 0, 0, 0};
    size_t base4 = (size_t)blockIdx.x * 2048;
    #pragma unroll
    for (int i = 0; i < 8; i++) {
        size_t f4 = base4 + (size_t)i * 256 + tid;
        float4 v = ((const float4*)gnn_pre)[f4];
        int n = ((int)(f4 >> 4)) & 1023;
        float4 nv = ((const float4*)net)[(size_t)n * 16 + (tid & 15)];
        float vv[4] = {v.x, v.y, v.z, v.w};
        float nn2[4] = {nv.x, nv.y, nv.z, nv.w};
        float ov[4];
        #pragma unroll
        for (int k = 0; k < 4; k++) {
            float y = (vv[k] - mean4[k]) * rs4[k] + bt4[k];
            y = y > 0.f ? y : 0.f;
            float o = y * nn2[k];
            ov[k] = o;
            s4[k] += o;
            q4[k] = fmaf(o, o, q4[k]);
        }
        float4 o4 = {ov[0], ov[1], ov[2], ov[3]};
        ((float4*)out_pre)[f4] = o4;
    }
    __shared__ float4 ls[256], lq[256];
    ls[tid] = make_float4(s4[0], s4[1], s4[2], s4[3]);
    lq[tid] = make_float4(q4[0], q4[1], q4[2], q4[3]);
    __syncthreads();
    if (tid < 16) {
        float4 S = ls[tid], Q = lq[tid];
        #pragma unroll
        for (int rr = 1; rr < 16; rr++) {
            float4 a = ls[tid + 16 * rr], b = lq[tid + 16 * rr];
            S.x += a.x; S.y += a.y; S.z += a.z; S.w += a.w;
            Q.x += b.x; Q.y += b.y; Q.z += b.z; Q.w += b.w;
        }
        atomicAdd(&stats[128 + tid * 4 + 0], S.x);
        atomicAdd(&stats[128 + tid * 4 + 1], S.y);
        atomicAdd(&stats[128 + tid * 4 + 2], S.z);
        atomicAdd(&stats[128 + tid * 4 + 3], S.w);
        atomicAdd(&stats[192 + tid * 4 + 0], Q.x);
        atomicAdd(&stats[192 + tid * 4 + 1], Q.y);
        atomicAdd(&stats[192 + tid * 4 + 2], Q.z);
        atomicAdd(&stats[192 + tid * 4 + 3], Q.w);
    }
}

// ---------------- K8: bn_out + relu + head ----------------
__global__ __launch_bounds__(256) void k_head(
    const float* __restrict__ out_pre, const float* __restrict__ stats,
    const float* __restrict__ gamma, const float* __restrict__ beta,
    const float* __restrict__ W_out, const float* __restrict__ b_out,
    float* __restrict__ out)
{
    int w = threadIdx.x >> 6, lane = threadIdx.x & 63;
    int r = blockIdx.x * 4 + w;
    float mean = stats[lane] * (1.0f / BNROWS);
    float var = stats[DD + lane] * (1.0f / BNROWS) - mean * mean;
    float rs = rsqrtf(var + 1e-5f);
    float y = (out_pre[(size_t)r * DD + lane] - mean) * rs * gamma[lane] + beta[lane];
    y = y > 0.f ? y : 0.f;
    float p = wave_sum(y * W_out[lane]);
    if (lane == 0) out[r] = p + b_out[0];
}

extern "C" void kernel_launch(void* const* d_in, const int* in_sizes, int n_in,
                              void* d_out, int out_size, void* d_ws, size_t ws_size,
                              hipStream_t stream)
{
    const float* data     = (const float*)d_in[0];
    const float* gumbel   = (const float*)d_in[1];
    const float* W_cond   = (const float*)d_in[2];
    const float* b_cond   = (const float*)d_in[3];
    const float* W_ap     = (const float*)d_in[4];
    const float* b_ap     = (const float*)d_in[5];
    const float* W_av     = (const float*)d_in[6];
    const float* W_r      = (const float*)d_in[7];
    const float* b_r      = (const float*)d_in[8];
    const float* e_base   = (const float*)d_in[9];
    const float* lr_u     = (const float*)d_in[10];
    const float* lr_v     = (const float*)d_in[11];
    const float* W_gnn    = (const float*)d_in[12];
    const float* att_i    = (const float*)d_in[13];
    const float* att_j    = (const float*)d_in[14];
    const float* att_em_i = (const float*)d_in[15];
    const float* att_em_j = (const float*)d_in[16];
    const float* b_gnn    = (const float*)d_in[17];
    const float* bn1_g    = (const float*)d_in[18];
    const float* bn1_b    = (const float*)d_in[19];
    const float* net      = (const float*)d_in[20];
    const float* bno_g    = (const float*)d_in[21];
    const float* bno_b    = (const float*)d_in[22];
    const float* W_out    = (const float*)d_in[23];
    const float* b_out    = (const float*)d_in[24];

    float* ws = (float*)d_ws;
    float* h_it   = ws + OFF_HIT;
    float* x_lin  = ws + OFF_XLIN;
    float* e_it   = ws + OFF_EIT;
    float* pi_t   = ws + OFF_PIT;
    float* mixed  = ws + OFF_MIXED;
    float* s_i    = ws + OFF_SI;
    float* s_j    = ws + OFF_SJ;
    float* gnn_pre = ws + OFF_GNN;
    float* out_pre = ws + OFF_OUTP;
    float* stats   = ws + OFF_STAT;          // 256: [128..255] bno stats
    float* bstats  = stats + 256;            // 32 banks x 128 (bn1 sum/sumsq)
    float* pnum    = stats + 4352;           // 2048
    float* pden    = stats + 6400;           // 32

    float* out0    = (float*)d_out;
    float* h_sys   = out0 + BB * NN;              // 32768
    float* pi_soft = out0 + BB * NN + BB * DD;    // 34816

    k_rows<<<BNROWS / 4, 256, 0, stream>>>(data, W_cond, b_cond, W_ap, b_ap, W_av, W_gnn,
                                           h_it, x_lin, e_it, stats);
    k_pool2<<<BB * 8, 256, 0, stream>>>(e_it, h_it, pnum, pden);
    k_route<<<1, 256, 0, stream>>>(pnum, pden, W_r, b_r, gumbel, h_sys, pi_soft, pi_t);
    k_mixed<<<BNROWS / 4, 256, 0, stream>>>(e_base, lr_u, lr_v, pi_t, x_lin,
                                            att_i, att_j, att_em_i, att_em_j, mixed, s_i, s_j);

    // ---- chunked score GEMM + fused selection/GAT (+banked bn1 stats) ----
    size_t ws_floats = ws_size / 4;
    size_t avail = ws_floats > OFF_SC ? ws_floats - OFF_SC : 0;
    int cb = (int)(avail / (size_t)(NN * NN));
    if (cb > BB) cb = BB;
    float* sc = ws + OFF_SC;
    if (cb < 1) { cb = 2; sc = h_it; }   // h_it dead after k_pool2; 2 b's fit in its 8MB
    for (int b0 = 0; b0 < BB; b0 += cb) {
        int c = (BB - b0) < cb ? (BB - b0) : cb;
        k_score<<<c * 128, 256, 0, stream>>>(mixed + (size_t)b0 * NN * DD, sc);
        k_selgat<<<c * 256, 256, 0, stream>>>(sc, b0, x_lin, s_i, s_j, b_gnn, gnn_pre, bstats);
    }

    k_bn1<<<256, 256, 0, stream>>>(gnn_pre, stats, bstats, bn1_g, bn1_b, net, out_pre);
    k_head<<<BNROWS / 4, 256, 0, stream>>>(out_pre, stats + 128, bno_g, bno_b, W_out, b_out, out0);
}

// Round 11
// 315.412 us; speedup vs baseline: 1.5549x; 1.1366x over previous
//
#include <hip/hip_runtime.h>
#include <math.h>

#define BB 32
#define NN 1024
#define FF 10
#define DD 64
#define MM 4
#define RR 8
#define KK 20
#define BNROWS (BB*NN)   // 32768

// ---- workspace layout (float offsets) ----
#define OFF_HIT   0ull           // h_it   [B,N,D]  2097152
#define OFF_XLIN  2097152ull     // x_lin  [B,N,D]  2097152
#define OFF_EIT   4194304ull     // e_it   [B,N]    32768
#define OFF_PIT   4227072ull     // pi_t   [B,M]    128
#define OFF_MIXED 4227200ull     // mixed  [B,N,D]  2097152
#define OFF_SI    6324352ull     // s_i    [B,N]    32768
#define OFF_SJ    6357120ull     // s_j    [B,N]    32768
#define OFF_GNN   7700608ull     // gnn_pre [B,N,D] 2097152
#define OFF_OUTP  9797760ull     // out_pre [B,N,D] 2097152
#define OFF_STAT  11894912ull    // stats 256 + banked bn1 4096 + pool num 2048 + den 32
#define OFF_SC    (OFF_STAT + 6464ull)  // score chunks

__device__ __forceinline__ float wave_sum(float v) {
    #pragma unroll
    for (int off = 32; off; off >>= 1) v += __shfl_xor(v, off);
    return v;
}
__device__ __forceinline__ float wave_max(float v) {
    #pragma unroll
    for (int off = 32; off; off >>= 1) v = fmaxf(v, __shfl_xor(v, off));
    return v;
}
__device__ __forceinline__ float lane_bcast(float v, int l) {
    return __int_as_float(__builtin_amdgcn_readlane(__float_as_int(v), l));
}

// ---------------- K1a: per-row h_it, x_lin, e_it (+ zero accum buffers) ----------------
__global__ __launch_bounds__(256) void k_rows(
    const float* __restrict__ data, const float* __restrict__ W_cond,
    const float* __restrict__ b_cond, const float* __restrict__ W_ap,
    const float* __restrict__ b_ap, const float* __restrict__ W_av,
    const float* __restrict__ W_gnn,
    float* __restrict__ h_it, float* __restrict__ x_lin, float* __restrict__ e_it,
    float* __restrict__ stats)
{
    if (blockIdx.x < 26) {
        int idx = blockIdx.x * 256 + threadIdx.x;
        if (idx < 6432) stats[idx] = 0.f;    // stats(256)+banked(4096)+num(2048)+den(32)
    }
    int w = threadIdx.x >> 6, lane = threadIdx.x & 63;
    int r = blockIdx.x * 4 + w;               // row in [0, B*N)
    const float* dr = data + r * FF;
    float df[FF];
    #pragma unroll
    for (int f = 0; f < FF; f++) df[f] = dr[f];
    float h = b_cond[lane], x = 0.f;
    #pragma unroll
    for (int f = 0; f < FF; f++) {
        h = fmaf(df[f], W_cond[f * DD + lane], h);
        x = fmaf(df[f], W_gnn[f * DD + lane], x);
    }
    h_it[r * DD + lane] = h;
    x_lin[r * DD + lane] = x;
    // h @ W_ap via readlane broadcast (VALU) instead of __shfl (LDS pipe)
    float acc = b_ap[lane];
    #pragma unroll
    for (int e2 = 0; e2 < DD; e2++)
        acc = fmaf(lane_bcast(h, e2), W_ap[e2 * DD + lane], acc);
    float lr = acc > 0.f ? acc : 0.2f * acc;
    float ep = wave_sum(lr * W_av[lane]);
    if (lane == 0) e_it[r] = ep;
}

// ---------------- K1b: parallel pool partials (no max shift; |e| small) ----------------
__global__ __launch_bounds__(256) void k_pool2(
    const float* __restrict__ e_it, const float* __restrict__ h_it,
    float* __restrict__ num, float* __restrict__ den)
{
    int w = threadIdx.x >> 6, lane = threadIdx.x & 63;
    int b = blockIdx.x >> 3, ch = blockIdx.x & 7;
    int base = b * NN + ch * 128 + w * 32;
    float acc = 0.f, dn = 0.f;
    #pragma unroll 4
    for (int i = 0; i < 32; i++) {
        float e = e_it[base + i];
        float wgt = expf(e);
        acc = fmaf(wgt, h_it[(size_t)(base + i) * DD + lane], acc);
        dn += wgt;
    }
    __shared__ float pa[4][DD];
    __shared__ float pd[4];
    pa[w][lane] = acc;
    if (lane == 0) pd[w] = dn;
    __syncthreads();
    if (w == 0) {
        float s = pa[0][lane] + pa[1][lane] + pa[2][lane] + pa[3][lane];
        atomicAdd(&num[b * DD + lane], s);
        if (lane == 0) atomicAdd(&den[b], pd[0] + pd[1] + pd[2] + pd[3]);
    }
}

// ---------------- K2: routing + h_sys normalize ----------------
__global__ void k_route(const float* __restrict__ num, const float* __restrict__ den,
                        const float* __restrict__ W_r, const float* __restrict__ b_r,
                        const float* __restrict__ gumbel,
                        float* __restrict__ h_sys, float* __restrict__ pi_soft,
                        float* __restrict__ pi_t)
{
    int tid = threadIdx.x;
    for (int i = tid; i < BB * DD; i += 256)
        h_sys[i] = num[i] / den[i >> 6];
    if (tid >= BB) return;
    int b = tid;
    float inv = 1.0f / den[b];
    float lg[MM];
    #pragma unroll
    for (int m = 0; m < MM; m++) lg[m] = b_r[m] + gumbel[b * MM + m];
    for (int d = 0; d < DD; d++) {
        float hv = num[b * DD + d] * inv;
        #pragma unroll
        for (int m = 0; m < MM; m++) lg[m] = fmaf(hv, W_r[d * MM + m], lg[m]);
    }
    float mx = fmaxf(fmaxf(lg[0], lg[1]), fmaxf(lg[2], lg[3]));
    float s = 0.f, p[MM];
    #pragma unroll
    for (int m = 0; m < MM; m++) { p[m] = expf(lg[m] - mx); s += p[m]; }
    #pragma unroll
    for (int m = 0; m < MM; m++) { p[m] /= s; pi_soft[b * MM + m] = p[m]; }
    int i1 = 0; float v1 = p[0];
    #pragma unroll
    for (int m = 1; m < MM; m++) if (p[m] > v1) { v1 = p[m]; i1 = m; }
    int i2 = -1; float v2 = -1.f;
    #pragma unroll
    for (int m = 0; m < MM; m++) if (m != i1 && p[m] > v2) { v2 = p[m]; i2 = m; }
    float norm = fmaxf(v1 + v2, 1e-12f);
    #pragma unroll
    for (int m = 0; m < MM; m++)
        pi_t[b * MM + m] = (m == i1 ? v1 : (m == i2 ? v2 : 0.f)) / norm;
}

// ---------------- K3: mixed embeddings + s_i/s_j (wave per row) ----------------
__global__ __launch_bounds__(256) void k_mixed(
    const float* __restrict__ e_base, const float* __restrict__ lr_u,
    const float* __restrict__ lr_v, const float* __restrict__ pi_t,
    const float* __restrict__ x_lin,
    const float* __restrict__ att_i, const float* __restrict__ att_j,
    const float* __restrict__ att_em_i, const float* __restrict__ att_em_j,
    float* __restrict__ mixed, float* __restrict__ s_i, float* __restrict__ s_j)
{
    int w = threadIdx.x >> 6, lane = threadIdx.x & 63;
    int r = blockIdx.x * 4 + w;
    int b = r >> 10, n = r & 1023;
    float LR[MM];
    #pragma unroll
    for (int m = 0; m < MM; m++) {
        float a = 0.f;
        #pragma unroll
        for (int rr = 0; rr < RR; rr++)
            a = fmaf(lr_u[(m * NN + n) * RR + rr], lr_v[(m * RR + rr) * DD + lane], a);
        LR[m] = a;
    }
    float eb = e_base[n * DD + lane];
    float mx = 0.f;
    #pragma unroll
    for (int m = 0; m < MM; m++) mx = fmaf(pi_t[b * MM + m], eb + LR[m], mx);
    mixed[(size_t)r * DD + lane] = mx;
    float x = x_lin[(size_t)r * DD + lane];
    float r1 = wave_sum(x * att_i[lane] + mx * att_em_i[lane]);
    float r2 = wave_sum(x * att_j[lane] + mx * att_em_j[lane]);
    if (lane == 0) { s_i[r] = r1; s_j[r] = r2; }
}

// ---------------- K4a: score GEMM, 128x128, swizzled conflict-free LDS ----------------
// swz(row) = ((row&4)<<4) | ((row>>3)<<2) | (row&3): b128 reads hit each bank 2x (free)
__global__ __launch_bounds__(256) void k_score(
    const float* __restrict__ mixed_chunk, float* __restrict__ sc)
{
    __shared__ float As[32 * 132];
    __shared__ float Bs[32 * 132];
    int t = threadIdx.x;
    int bb = blockIdx.x >> 6;
    int rr = blockIdx.x & 63;
    int it = rr >> 3, jt = rr & 7;
    int i0 = it * 128, j0 = jt * 128;
    const float* mb = mixed_chunk + (size_t)bb * NN * DD;

    int tx = t & 15, ty = t >> 4;            // tx: 8 j's, ty: 8 i's
    float acc[8][8];
    #pragma unroll
    for (int a = 0; a < 8; a++)
        #pragma unroll
        for (int bj = 0; bj < 8; bj++) acc[a][bj] = 0.f;

    int rowi[4], qi[4], swi[4];
    #pragma unroll
    for (int c = 0; c < 4; c++) {
        int id = t + c * 256;                 // 0..1023
        rowi[c] = (id & 15) | ((id >> 7) << 4);
        qi[c] = (id >> 4) & 7;
        swi[c] = ((rowi[c] & 4) << 4) | ((rowi[c] >> 3) << 2) | (rowi[c] & 3);
    }

    float4 pa[4], pb[4];
    #pragma unroll
    for (int c = 0; c < 4; c++) {            // prefetch half 0
        pa[c] = *(const float4*)(mb + (size_t)(i0 + rowi[c]) * DD + qi[c] * 4);
        pb[c] = *(const float4*)(mb + (size_t)(j0 + rowi[c]) * DD + qi[c] * 4);
    }
    for (int hh = 0; hh < 2; hh++) {
        if (hh) __syncthreads();
        #pragma unroll
        for (int c = 0; c < 4; c++) {
            int pos = qi[c] * 4 * 132 + swi[c];
            As[pos] = pa[c].x; As[pos + 132] = pa[c].y; As[pos + 264] = pa[c].z; As[pos + 396] = pa[c].w;
            Bs[pos] = pb[c].x; Bs[pos + 132] = pb[c].y; Bs[pos + 264] = pb[c].z; Bs[pos + 396] = pb[c].w;
        }
        __syncthreads();
        if (hh == 0) {                        // prefetch half 1 during compute of half 0
            #pragma unroll
            for (int c = 0; c < 4; c++) {
                pa[c] = *(const float4*)(mb + (size_t)(i0 + rowi[c]) * DD + 32 + qi[c] * 4);
                pb[c] = *(const float4*)(mb + (size_t)(j0 + rowi[c]) * DD + 32 + qi[c] * 4);
            }
        }
        #pragma unroll 4
        for (int d = 0; d < 32; d++) {
            float4 a0 = *(const float4*)&As[d * 132 + ty * 4];        // rows ty*8+0..3
            float4 a1 = *(const float4*)&As[d * 132 + 64 + ty * 4];   // rows ty*8+4..7
            float4 b0 = *(const float4*)&Bs[d * 132 + tx * 4];
            float4 b1 = *(const float4*)&Bs[d * 132 + 64 + tx * 4];
            float av[8] = {a0.x, a0.y, a0.z, a0.w, a1.x, a1.y, a1.z, a1.w};
            float bv[8] = {b0.x, b0.y, b0.z, b0.w, b1.x, b1.y, b1.z, b1.w};
            #pragma unroll
            for (int a = 0; a < 8; a++)
                #pragma unroll
                for (int bj = 0; bj < 8; bj++)
                    acc[a][bj] = fmaf(av[a], bv[bj], acc[a][bj]);
        }
    }

    float* out = sc + ((size_t)bb * NN + i0 + ty * 8) * NN + j0 + tx * 8;
    #pragma unroll
    for (int a = 0; a < 8; a++) {
        float4 o0 = {acc[a][0], acc[a][1], acc[a][2], acc[a][3]};
        float4 o1 = {acc[a][4], acc[a][5], acc[a][6], acc[a][7]};
        *(float4*)(out + (size_t)a * NN) = o0;
        *(float4*)(out + (size_t)a * NN + 4) = o1;
    }
}

// ---------------- K4b: fused top-20 selection + GAT + banked bn1 stats ----------------
// wave per row. slot s of lane l -> j = (s>>2)*256 + l*4 + (s&3)
// bn1 stats go to 32 banks (blockIdx&31) -> per-bank fan-in 256 blocks (r6 lesson:
// 8192-block fan-in to one cache-line set serialized the whole dispatch, ~200us).
__global__ __launch_bounds__(256) void k_selgat(
    const float* __restrict__ sc, int b0,
    const float* __restrict__ x_lin, const float* __restrict__ s_i,
    const float* __restrict__ s_j, const float* __restrict__ b_gnn,
    float* __restrict__ gnn_pre, float* __restrict__ bstats)
{
    int w = threadIdx.x >> 6, lane = threadIdx.x & 63;
    int lr = blockIdx.x * 4 + w;                 // local row within chunk
    int r = b0 * NN + lr;                        // global row
    int b = r >> 10, n = r & 1023;
    const float* row = sc + (size_t)lr * NN;

    unsigned uk[16];
    #pragma unroll
    for (int c = 0; c < 4; c++) {
        float4 v = *(const float4*)(row + c * 256 + lane * 4);
        float vv[4] = {v.x, v.y, v.z, v.w};
        #pragma unroll
        for (int q = 0; q < 4; q++) {
            unsigned u = __float_as_uint(vv[q]);
            uk[c * 4 + q] = u ^ (((unsigned)((int)u >> 31)) | 0x80000000u);
        }
    }
    // per-lane max
    unsigned mx = uk[0];
    #pragma unroll
    for (int i = 1; i < 16; i++) mx = uk[i] > mx ? uk[i] : mx;
    // bitonic sort-64 (desc) of lane maxima -> tau = 20th largest (<= true 20th value)
    unsigned sv = mx;
    #pragma unroll
    for (int blk = 2; blk <= 64; blk <<= 1) {
        #pragma unroll
        for (int dist = blk >> 1; dist >= 1; dist >>= 1) {
            unsigned pv = (unsigned)__shfl_xor((int)sv, dist);
            bool up = (lane & blk) == 0;
            bool upper = (lane & dist) == 0;
            bool g = sv > pv;
            sv = (((g == upper) == up)) ? sv : pv;
        }
    }
    unsigned tau = (unsigned)__shfl((int)sv, 19);

    // ballot-prefix compact candidates >= tau into LDS
    __shared__ unsigned skey[4][64];
    __shared__ int sjj[4][64];
    int base = 0;
    #pragma unroll
    for (int s = 0; s < 16; s++) {
        bool q = uk[s] >= tau;
        unsigned long long m = __ballot(q);
        if (q) {
            int pos = base + __popcll(m & ((1ull << lane) - 1ull));
            if (pos < 64) {
                skey[w][pos] = uk[s];
                sjj[w][pos] = ((s >> 2) << 8) + lane * 4 + (s & 3);
            }
        }
        base += __popcll(m);
    }
    int C = base;   // >= 20 guaranteed

    float vk = -INFINITY; int ik = 0;
    if (C <= 64) {
        unsigned ck = 0u; int cj = 0x7FFFFFFF;
        if (lane < C) { ck = skey[w][lane]; cj = sjj[w][lane]; }
        if (C <= 32) {
            #pragma unroll
            for (int blk = 2; blk <= 32; blk <<= 1)
                #pragma unroll
                for (int dist = blk >> 1; dist >= 1; dist >>= 1) {
                    unsigned pk = (unsigned)__shfl_xor((int)ck, dist);
                    int pj = __shfl_xor(cj, dist);
                    bool up = (lane & blk) == 0;
                    bool upper = (lane & dist) == 0;
                    bool g = (ck > pk) || (ck == pk && cj < pj);
                    bool keep = ((g == upper) == up);
                    ck = keep ? ck : pk; cj = keep ? cj : pj;
                }
        } else {
            #pragma unroll
            for (int blk = 2; blk <= 64; blk <<= 1)
                #pragma unroll
                for (int dist = blk >> 1; dist >= 1; dist >>= 1) {
                    unsigned pk = (unsigned)__shfl_xor((int)ck, dist);
                    int pj = __shfl_xor(cj, dist);
                    bool up = (lane & blk) == 0;
                    bool upper = (lane & dist) == 0;
                    bool g = (ck > pk) || (ck == pk && cj < pj);
                    bool keep = ((g == upper) == up);
                    ck = keep ? ck : pk; cj = keep ? cj : pj;
                }
        }
        if (lane < KK) {
            unsigned u = (ck & 0x80000000u) ? (ck ^ 0x80000000u) : ~ck;
            vk = __uint_as_float(u);
            ik = cj;
        }
    } else {
        // rare fallback: full 20-round extraction
        for (int k = 0; k < KK; k++) {
            unsigned bm = uk[0]; int bsl = 0;
            #pragma unroll
            for (int i = 1; i < 16; i++) if (uk[i] > bm) { bm = uk[i]; bsl = i; }
            unsigned wm = bm;
            #pragma unroll
            for (int off = 32; off; off >>= 1) {
                unsigned tt = (unsigned)__shfl_xor((int)wm, off);
                wm = tt > wm ? tt : wm;
            }
            unsigned long long ball = __ballot(bm == wm);
            int winner = (int)__builtin_ctzll(ball);
            int slotw = __shfl(bsl, winner);
            int jw = ((slotw >> 2) << 8) + winner * 4 + (slotw & 3);
            unsigned u2 = (wm & 0x80000000u) ? (wm ^ 0x80000000u) : ~wm;
            if (lane == k) { vk = __uint_as_float(u2); ik = jw; }
            if (lane == winner) uk[bsl] = 0u;
        }
    }

    // ---- GAT (operands already in registers) ----
    float m1 = wave_max(vk);
    float ek = (lane < KK) ? expf(vk - m1) : 0.f;
    float s1v = wave_sum(ek);
    float wk = ek / s1v;
    float si = s_i[r], sjn = s_j[r];
    float a = -INFINITY;
    if (lane < KK) {
        float sjk = s_j[(b << 10) + ik];
        float t2 = si + sjk;
        a = (ik == n) ? -INFINITY : (t2 > 0.f ? t2 : 0.2f * t2);
    }
    float ts = si + sjn;
    float aself = ts > 0.f ? ts : 0.2f * ts;
    float am = wave_max(fmaxf(a, aself));
    float ea = (lane < KK && a != -INFINITY) ? expf(a - am) : 0.f;
    float es = expf(aself - am);
    float ssm = wave_sum(ea) + es;
    float wnb = (ea / ssm) * wk;
    float wself = es / ssm;
    float acc = b_gnn[lane] + wself * x_lin[(size_t)r * DD + lane];
    #pragma unroll
    for (int k = 0; k < KK; k++) {
        int jk = __shfl(ik, k);
        float wv = __shfl(wnb, k);
        acc = fmaf(wv, x_lin[((size_t)(b << 10) + jk) * DD + lane], acc);
    }
    gnn_pre[(size_t)r * DD + lane] = acc;

    // ---- bn1 per-channel stats partials (lane == channel), 32-way banked ----
    __shared__ float ps[4][64], pq[4][64];
    ps[w][lane] = acc;
    pq[w][lane] = acc * acc;
    __syncthreads();
    if (w == 0) {
        float s = ps[0][lane] + ps[1][lane] + ps[2][lane] + ps[3][lane];
        float q2 = pq[0][lane] + pq[1][lane] + pq[2][lane] + pq[3][lane];
        float* bk = bstats + (size_t)(blockIdx.x & 31) * 128;
        atomicAdd(&bk[lane], s);
        atomicAdd(&bk[DD + lane], q2);
    }
}

// ---------------- K7: bn1 + relu + embed multiply (+ bno stats partials) ----------------
__global__ __launch_bounds__(256) void k_bn1(
    const float* __restrict__ gnn_pre, float* __restrict__ stats,
    const float* __restrict__ bstats,
    const float* __restrict__ gamma, const float* __restrict__ beta,
    const float* __restrict__ net, float* __restrict__ out_pre)
{
    int tid = threadIdx.x;
    int d0 = (tid & 15) * 4;
    float mean4[4], rs4[4], bt4[4];
    #pragma unroll
    for (int k = 0; k < 4; k++) {
        float s = 0.f, q = 0.f;
        #pragma unroll 8
        for (int bk = 0; bk < 32; bk++) {
            s += bstats[bk * 128 + d0 + k];
            q += bstats[bk * 128 + 64 + d0 + k];
        }
        float mu = s * (1.0f / BNROWS);
        float var = q * (1.0f / BNROWS) - mu * mu;
        mean4[k] = mu;
        rs4[k] = rsqrtf(var + 1e-5f) * gamma[d0 + k];
        bt4[k] = beta[d0 + k];
    }
    float s4[4] = {0, 0, 0, 0}, q4[4] = {0, 0, 0, 0};
    size_t base4 = (size_t)blockIdx.x * 2048;     // float4 units (128 rows/block)
    #pragma unroll
    for (int i = 0; i < 8; i++) {
        size_t f4 = base4 + (size_t)i * 256 + tid;
        float4 v = ((const float4*)gnn_pre)[f4];
        int n = ((int)(f4 >> 4)) & 1023;
        float4 nv = ((const float4*)net)[(size_t)n * 16 + (tid & 15)];
        float vv[4] = {v.x, v.y, v.z, v.w};
        float nn2[4] = {nv.x, nv.y, nv.z, nv.w};
        float ov[4];
        #pragma unroll
        for (int k = 0; k < 4; k++) {
            float y = (vv[k] - mean4[k]) * rs4[k] + bt4[k];
            y = y > 0.f ? y : 0.f;
            float o = y * nn2[k];
            ov[k] = o;
            s4[k] += o;
            q4[k] = fmaf(o, o, q4[k]);
        }
        float4 o4 = {ov[0], ov[1], ov[2], ov[3]};
        ((float4*)out_pre)[f4] = o4;
    }
    __shared__ float4 ls[256], lq[256];
    ls[tid] = make_float4(s4[0], s4[1], s4[2], s4[3]);
    lq[tid] = make_float4(q4[0], q4[1], q4[2], q4[3]);
    __syncthreads();
    if (tid < 16) {
        float4 S = ls[tid], Q = lq[tid];
        #pragma unroll
        for (int rr = 1; rr < 16; rr++) {
            float4 a = ls[tid + 16 * rr], b = lq[tid + 16 * rr];
            S.x += a.x; S.y += a.y; S.z += a.z; S.w += a.w;
            Q.x += b.x; Q.y += b.y; Q.z += b.z; Q.w += b.w;
        }
        atomicAdd(&stats[128 + tid * 4 + 0], S.x);
        atomicAdd(&stats[128 + tid * 4 + 1], S.y);
        atomicAdd(&stats[128 + tid * 4 + 2], S.z);
        atomicAdd(&stats[128 + tid * 4 + 3], S.w);
        atomicAdd(&stats[192 + tid * 4 + 0], Q.x);
        atomicAdd(&stats[192 + tid * 4 + 1], Q.y);
        atomicAdd(&stats[192 + tid * 4 + 2], Q.z);
        atomicAdd(&stats[192 + tid * 4 + 3], Q.w);
    }
}

// ---------------- K8: bn_out + relu + head ----------------
__global__ __launch_bounds__(256) void k_head(
    const float* __restrict__ out_pre, const float* __restrict__ stats,
    const float* __restrict__ gamma, const float* __restrict__ beta,
    const float* __restrict__ W_out, const float* __restrict__ b_out,
    float* __restrict__ out)
{
    int w = threadIdx.x >> 6, lane = threadIdx.x & 63;
    int r = blockIdx.x * 4 + w;
    float mean = stats[lane] * (1.0f / BNROWS);
    float var = stats[DD + lane] * (1.0f / BNROWS) - mean * mean;
    float rs = rsqrtf(var + 1e-5f);
    float y = (out_pre[(size_t)r * DD + lane] - mean) * rs * gamma[lane] + beta[lane];
    y = y > 0.f ? y : 0.f;
    float p = wave_sum(y * W_out[lane]);
    if (lane == 0) out[r] = p + b_out[0];
}

extern "C" void kernel_launch(void* const* d_in, const int* in_sizes, int n_in,
                              void* d_out, int out_size, void* d_ws, size_t ws_size,
                              hipStream_t stream)
{
    const float* data     = (const float*)d_in[0];
    const float* gumbel   = (const float*)d_in[1];
    const float* W_cond   = (const float*)d_in[2];
    const float* b_cond   = (const float*)d_in[3];
    const float* W_ap     = (const float*)d_in[4];
    const float* b_ap     = (const float*)d_in[5];
    const float* W_av     = (const float*)d_in[6];
    const float* W_r      = (const float*)d_in[7];
    const float* b_r      = (const float*)d_in[8];
    const float* e_base   = (const float*)d_in[9];
    const float* lr_u     = (const float*)d_in[10];
    const float* lr_v     = (const float*)d_in[11];
    const float* W_gnn    = (const float*)d_in[12];
    const float* att_i    = (const float*)d_in[13];
    const float* att_j    = (const float*)d_in[14];
    const float* att_em_i = (const float*)d_in[15];
    const float* att_em_j = (const float*)d_in[16];
    const float* b_gnn    = (const float*)d_in[17];
    const float* bn1_g    = (const float*)d_in[18];
    const float* bn1_b    = (const float*)d_in[19];
    const float* net      = (const float*)d_in[20];
    const float* bno_g    = (const float*)d_in[21];
    const float* bno_b    = (const float*)d_in[22];
    const float* W_out    = (const float*)d_in[23];
    const float* b_out    = (const float*)d_in[24];

    float* ws = (float*)d_ws;
    float* h_it   = ws + OFF_HIT;
    float* x_lin  = ws + OFF_XLIN;
    float* e_it   = ws + OFF_EIT;
    float* pi_t   = ws + OFF_PIT;
    float* mixed  = ws + OFF_MIXED;
    float* s_i    = ws + OFF_SI;
    float* s_j    = ws + OFF_SJ;
    float* gnn_pre = ws + OFF_GNN;
    float* out_pre = ws + OFF_OUTP;
    float* stats   = ws + OFF_STAT;          // 256: [128..255] bno stats
    float* bstats  = stats + 256;            // 32 banks x 128 (bn1 sum/sumsq)
    float* pnum    = stats + 4352;           // 2048
    float* pden    = stats + 6400;           // 32

    float* out0    = (float*)d_out;
    float* h_sys   = out0 + BB * NN;              // 32768
    float* pi_soft = out0 + BB * NN + BB * DD;    // 34816

    k_rows<<<BNROWS / 4, 256, 0, stream>>>(data, W_cond, b_cond, W_ap, b_ap, W_av, W_gnn,
                                           h_it, x_lin, e_it, stats);
    k_pool2<<<BB * 8, 256, 0, stream>>>(e_it, h_it, pnum, pden);
    k_route<<<1, 256, 0, stream>>>(pnum, pden, W_r, b_r, gumbel, h_sys, pi_soft, pi_t);
    k_mixed<<<BNROWS / 4, 256, 0, stream>>>(e_base, lr_u, lr_v, pi_t, x_lin,
                                            att_i, att_j, att_em_i, att_em_j, mixed, s_i, s_j);

    // ---- chunked score GEMM + fused selection/GAT (+banked bn1 stats) ----
    size_t ws_floats = ws_size / 4;
    size_t avail = ws_floats > OFF_SC ? ws_floats - OFF_SC : 0;
    int cb = (int)(avail / (size_t)(NN * NN));
    if (cb > BB) cb = BB;
    float* sc = ws + OFF_SC;
    if (cb < 1) { cb = 2; sc = h_it; }   // h_it dead after k_pool2; 2 b's fit in its 8MB
    for (int b0 = 0; b0 < BB; b0 += cb) {
        int c = (BB - b0) < cb ? (BB - b0) : cb;
        k_score<<<c * 64, 256, 0, stream>>>(mixed + (size_t)b0 * NN * DD, sc);
        k_selgat<<<c * 256, 256, 0, stream>>>(sc, b0, x_lin, s_i, s_j, b_gnn, gnn_pre, bstats);
    }

    k_bn1<<<256, 256, 0, stream>>>(gnn_pre, stats, bstats, bn1_g, bn1_b, net, out_pre);
    k_head<<<BNROWS / 4, 256, 0, stream>>>(out_pre, stats + 128, bno_g, bno_b, W_out, b_out, out0);
}